// Round 10
// baseline (333.306 us; speedup 1.0000x reference)
//
#include <hip/hip_runtime.h>
#include <hip/hip_bf16.h>
#include <cstdint>
#include <cstddef>

#define B_ 2
#define S_ 2048
#define NH_ 16
#define NKV_ 4
#define HD_ 128
#define QDIM_ 2048
#define KVDIM_ 512
#define QKV_ 3072

typedef __attribute__((ext_vector_type(8))) short short8;
typedef __attribute__((ext_vector_type(4))) short bhalf4;   // short4 collides with HIP
typedef __attribute__((ext_vector_type(4))) float float4v;

__device__ __forceinline__ float bf2f(short u) {
  union { unsigned int i; float f; } v;
  v.i = ((unsigned int)(unsigned short)u) << 16;
  return v.f;
}
__device__ __forceinline__ short f2bf(float f) {
  union { float f; unsigned int i; } v; v.f = f;
  unsigned int x = v.i;
  x += 0x7fffu + ((x >> 16) & 1u);   // RNE
  return (short)(x >> 16);
}

#if __has_builtin(__builtin_amdgcn_exp2f)
__device__ __forceinline__ float exp2fast(float x) { return __builtin_amdgcn_exp2f(x); }
#else
__device__ __forceinline__ float exp2fast(float x) { return exp2f(x); }
#endif

// packed f32x2 -> bf16x2 (T12 recipe; no builtin on gfx950)
__device__ __forceinline__ unsigned int cvt_pk_bf16(float a, float b) {
  unsigned int r;
  asm("v_cvt_pk_bf16_f32 %0, %1, %2" : "=v"(r) : "v"(a), "v"(b));
  return r;
}

__device__ __forceinline__ void async_copy16(void* lds, const void* g) {
  __builtin_amdgcn_global_load_lds(
      (const __attribute__((address_space(1))) void*)g,
      (__attribute__((address_space(3))) void*)lds, 16, 0, 0);
}

// ---------------------------------------------------------------------------
// fp32 -> bf16 converts (HBM-bound). Two-range fused variant saves a launch.
// ---------------------------------------------------------------------------
__device__ __forceinline__ void cvt8(const float* f, short* d) {
  float4v a = *(const float4v*)(f);
  float4v b = *(const float4v*)(f + 4);
  short8 r;
#pragma unroll
  for (int e = 0; e < 4; ++e) { r[e] = f2bf(a[e]); r[4 + e] = f2bf(b[e]); }
  *(short8*)d = r;
}

__global__ void f32_to_bf16(const float* __restrict__ src, short* __restrict__ dst,
                            int n8) {
  int id = blockIdx.x * 256 + threadIdx.x;
  if (id >= n8) return;
  cvt8(src + (size_t)id * 8, dst + (size_t)id * 8);
}

__global__ void f32_to_bf16_2(const float* __restrict__ s0, short* __restrict__ d0,
                              int n0_8, const float* __restrict__ s1,
                              short* __restrict__ d1) {
  int id = blockIdx.x * 256 + threadIdx.x;
  if (id < n0_8) {
    cvt8(s0 + (size_t)id * 8, d0 + (size_t)id * 8);
  } else {
    int j = id - n0_8;
    cvt8(s1 + (size_t)j * 8, d1 + (size_t)j * 8);
  }
}

// ---------------------------------------------------------------------------
// NT GEMM, 128x128 tile (m97 structure; verified). Used for both GEMMs —
// the R8/R9 256^2 pipelined port was correct-at-last but 10 us slower
// (192-block grid = 25% idle CUs, 1 block/CU, 2-phase granularity lost the
// template's gain), so the verified kernel stays.
// ---------------------------------------------------------------------------
template <int N, int K, bool CF32>
__global__ __launch_bounds__(256)
void gemm_nt_bf16(const short* __restrict__ A, const short* __restrict__ Bm,
                  void* __restrict__ Cp) {
  __shared__ __align__(16) short sA[128 * 32];
  __shared__ __align__(16) short sB[128 * 32];
  const int tid = threadIdx.x;
  const int m0 = blockIdx.y * 128, n0 = blockIdx.x * 128;
  const int wave = tid >> 6, lane = tid & 63;
  const int wm = (wave & 1) << 6, wn = (wave >> 1) << 6;
  const int lm = lane & 15, kg = lane >> 4;

  float4v acc[4][4];
#pragma unroll
  for (int i = 0; i < 4; ++i)
#pragma unroll
    for (int j = 0; j < 4; ++j)
      acc[i][j] = (float4v){0.f, 0.f, 0.f, 0.f};

  const int r0 = tid >> 2, c0 = tid & 3;
  const short* gA0 = A + (size_t)(m0 + r0) * K + c0 * 8;
  const short* gA1 = gA0 + (size_t)64 * K;
  const short* gB0 = Bm + (size_t)(n0 + r0) * K + c0 * 8;
  const short* gB1 = gB0 + (size_t)64 * K;
  short* lA0 = sA + tid * 8;
  short* lA1 = sA + 2048 + tid * 8;
  short* lB0 = sB + tid * 8;
  short* lB1 = sB + 2048 + tid * 8;

  for (int k0 = 0; k0 < K; k0 += 32) {
    async_copy16(lA0, gA0 + k0);
    async_copy16(lA1, gA1 + k0);
    async_copy16(lB0, gB0 + k0);
    async_copy16(lB1, gB1 + k0);
    __syncthreads();

    short8 a[4], b[4];
#pragma unroll
    for (int i = 0; i < 4; ++i)
      a[i] = *(const short8*)(sA + (wm + i * 16 + lm) * 32 + kg * 8);
#pragma unroll
    for (int j = 0; j < 4; ++j)
      b[j] = *(const short8*)(sB + (wn + j * 16 + lm) * 32 + kg * 8);
#pragma unroll
    for (int i = 0; i < 4; ++i)
#pragma unroll
      for (int j = 0; j < 4; ++j)
        acc[i][j] = __builtin_amdgcn_mfma_f32_16x16x32_bf16(a[i], b[j], acc[i][j], 0, 0, 0);
    __syncthreads();
  }

#pragma unroll
  for (int i = 0; i < 4; ++i) {
    const int rb = m0 + wm + i * 16 + kg * 4;
#pragma unroll
    for (int j = 0; j < 4; ++j) {
      const int cc = n0 + wn + j * 16 + lm;
#pragma unroll
      for (int r = 0; r < 4; ++r) {
        if constexpr (CF32)
          ((float*)Cp)[(size_t)(rb + r) * N + cc] = acc[i][j][r];
        else
          ((short*)Cp)[(size_t)(rb + r) * N + cc] = f2bf(acc[i][j][r]);
      }
    }
  }
}

// ---------------------------------------------------------------------------
// RoPE + split/layout; Q pre-scaled by (1/sqrt(HD)) * log2(e).
// ---------------------------------------------------------------------------
__global__ void rope_split(const short* __restrict__ xqkv, const float* __restrict__ freqs,
                           short* __restrict__ Qr, short* __restrict__ Kr,
                           short* __restrict__ Vv) {
  const int id = blockIdx.x * 256 + threadIdx.x;
  const int i = id / (QKV_ / 8);   // token 0..4095
  const int c8 = id % (QKV_ / 8);
  const int col = c8 * 8;
  const int b = i >> 11, s = i & (S_ - 1);
  short8 xv = *(const short8*)(xqkv + (size_t)i * QKV_ + col);
  if (col < QDIM_ + KVDIM_) {
    int d;
    short* dst;
    float sc;
    if (col < QDIM_) {
      int hh = col >> 7; d = col & 127;
      dst = Qr + ((size_t)(b * NH_ + hh) * S_ + s) * HD_ + d;
      sc = 0.12751744543795287f;   // (1/sqrt(128)) * log2(e)
    } else {
      int cc = col - QDIM_;
      int hh = cc >> 7; d = cc & 127;
      dst = Kr + ((size_t)(b * NKV_ + hh) * S_ + s) * HD_ + d;
      sc = 1.0f;
    }
    const float* fp = freqs + (size_t)s * HD_ + d;
    float4v fa = *(const float4v*)(fp);
    float4v fb = *(const float4v*)(fp + 4);
    float ff[8] = {fa[0], fa[1], fa[2], fa[3], fb[0], fb[1], fb[2], fb[3]};
    short8 ov;
#pragma unroll
    for (int pp = 0; pp < 4; ++pp) {
      float t0 = bf2f(xv[2 * pp]), t1 = bf2f(xv[2 * pp + 1]);
      float f0 = ff[2 * pp], f1 = ff[2 * pp + 1];
      ov[2 * pp]     = f2bf((t0 * f1 - t1 * f0) * sc);
      ov[2 * pp + 1] = f2bf((t0 * f0 + t1 * f1) * sc);
    }
    *(short8*)dst = ov;
  } else {
    int cc = col - QDIM_ - KVDIM_;
    int hh = cc >> 7, d = cc & 127;
    *(short8*)(Vv + ((size_t)(b * NKV_ + hh) * S_ + s) * HD_ + d) = xv;
  }
}

// ---------------------------------------------------------------------------
// V transpose: Vv [b][kvh][s][d] -> Vt [b][kvh][d][s]. LDS-tiled 64x64.
// ---------------------------------------------------------------------------
__global__ void transpose_v(const short* __restrict__ Vv, short* __restrict__ Vt) {
  __shared__ short t[64][72];
  const int s0 = blockIdx.x * 64, d0 = blockIdx.y * 64;
  const short* src = Vv + (size_t)blockIdx.z * S_ * HD_;
  short* dst = Vt + (size_t)blockIdx.z * S_ * HD_;
  const int tid = threadIdx.x;
#pragma unroll
  for (int c = 0; c < 2; ++c) {
    int ch = tid + 256 * c;
    int row = ch >> 3, kc = ch & 7;
    *(short8*)(&t[row][kc * 8]) =
        *(const short8*)(src + (size_t)(s0 + row) * HD_ + d0 + kc * 8);
  }
  __syncthreads();
#pragma unroll
  for (int c = 0; c < 2; ++c) {
    int ch = tid + 256 * c;
    int drow = ch >> 3, sc = ch & 7;
    short8 w;
#pragma unroll
    for (int j = 0; j < 8; ++j) w[j] = t[sc * 8 + j][drow];
    *(short8*)(dst + (size_t)(d0 + drow) * S_ + s0 + sc * 8) = w;
  }
}

// ---------------------------------------------------------------------------
// Flash attention v10 (banked, 87.5 us): 2 q-subtiles/wave, QBLK=128, TK=64.
// Each LDS K/V fragment read feeds 2 MFMAs (conflicts halved vs v8, no
// spill at VGPR 104). exp2-domain softmax, defer-max THR=4, cvt_pk P->bf16.
// ---------------------------------------------------------------------------
#define TK 64

__global__ __launch_bounds__(256, 2)
void attn_causal(const short* __restrict__ Q, const short* __restrict__ K,
                 const short* __restrict__ Vt, short* __restrict__ O) {
  const int bh = blockIdx.x;                 // 0..31
  const int by = blockIdx.y;                 // 0..15
  const int qt = (by < 8) ? (15 - by) : (by - 8);   // LPT pairing
  const int b = bh >> 4, h = bh & 15;
  const int kvh = h >> 2;
  const int tid = threadIdx.x, wave = tid >> 6, lane = tid & 63;
  const int lm = lane & 15, kg = lane >> 4;

  __shared__ __align__(16) short sK[TK * HD_];    // 16 KB, swizzled
  __shared__ __align__(16) short sVt[HD_ * TK];   // 16 KB, swizzled

  const short* Qb = Q + (size_t)(b * NH_ + h) * S_ * HD_;
  const short* Kb = K + (size_t)(b * NKV_ + kvh) * S_ * HD_;
  const short* Vtb = Vt + (size_t)(b * NKV_ + kvh) * S_ * HD_;

  auto stageK = [&](int k0) {
#pragma unroll
    for (int c = 0; c < 4; ++c) {
      int ch = tid + 256 * c;
      int row = ch >> 4, kc = ch & 15;
      async_copy16(sK + ch * 8,
                   Kb + (size_t)(k0 + row) * HD_ + (kc ^ (row & 7)) * 8);
    }
  };
  auto stageV = [&](int k0) {
#pragma unroll
    for (int c = 0; c < 4; ++c) {
      int ch = tid + 256 * c;
      int row = ch >> 3, kc = ch & 7;
      async_copy16(sVt + ch * 8,
                   Vtb + (size_t)row * S_ + k0 + (kc ^ (row & 7)) * 8);
    }
  };

  // wave owns 32 contiguous q rows: rows qbase + u*16, u = 0,1
  const int qbase = qt * 128 + wave * 32 + lm;
  short8 qf[2][4];
#pragma unroll
  for (int u = 0; u < 2; ++u)
#pragma unroll
    for (int kk = 0; kk < 4; ++kk)
      qf[u][kk] = *(const short8*)(Qb + (size_t)(qbase + u * 16) * HD_ +
                                   kk * 32 + kg * 8);

  float mcur[2] = {-1e9f, -1e9f}, lcur[2] = {0.f, 0.f};
  float4v o[2][8];
#pragma unroll
  for (int u = 0; u < 2; ++u)
#pragma unroll
    for (int df = 0; df < 8; ++df) o[u][df] = (float4v){0.f, 0.f, 0.f, 0.f};

  stageK(0);
  const int nst = 2 * qt + 2;
  for (int s = 0; s < nst; ++s) {
    const int k0 = s * TK;
    const bool last = (s == nst - 1);
    const bool maskstep = (s >= nst - 2);   // 128-row tile spans 2 diag tiles

    __syncthreads();           // B1: K[s] landed; all waves done PV[s-1]
    stageV(k0);                // V[s]; lands by B2

    // S^T = K * Q^T for both q-subtiles; each af read feeds 2 MFMAs
    float4v sf[2][4];
#pragma unroll
    for (int u = 0; u < 2; ++u)
#pragma unroll
      for (int mj = 0; mj < 4; ++mj) sf[u][mj] = (float4v){0.f, 0.f, 0.f, 0.f};
    __builtin_amdgcn_s_setprio(1);
#pragma unroll
    for (int kk = 0; kk < 4; ++kk) {
      int kd = kk * 4 + kg;
#pragma unroll
      for (int mj = 0; mj < 4; ++mj) {
        int row = mj * 16 + lm;
        short8 af = *(const short8*)(sK + row * HD_ + (kd ^ (row & 7)) * 8);
        sf[0][mj] = __builtin_amdgcn_mfma_f32_16x16x32_bf16(af, qf[0][kk], sf[0][mj], 0, 0, 0);
        sf[1][mj] = __builtin_amdgcn_mfma_f32_16x16x32_bf16(af, qf[1][kk], sf[1][mj], 0, 0, 0);
      }
    }
    __builtin_amdgcn_s_setprio(0);

    if (maskstep) {   // causal mask, per subtile (harmless where all pass)
#pragma unroll
      for (int u = 0; u < 2; ++u) {
        const int qg = qbase + u * 16;
#pragma unroll
        for (int mj = 0; mj < 4; ++mj)
#pragma unroll
          for (int r = 0; r < 4; ++r) {
            int kcol = k0 + mj * 16 + kg * 4 + r;
            sf[u][mj][r] = (kcol <= qg) ? sf[u][mj][r] : -3e38f;
          }
      }
    }

    // online softmax (exp2 domain), defer-max THR=4, per subtile
    bhalf4 pb[2][4];
    bool need[2];
    float alpha[2];
#pragma unroll
    for (int u = 0; u < 2; ++u) {
      float mx = -3e38f;
#pragma unroll
      for (int mj = 0; mj < 4; ++mj)
#pragma unroll
        for (int r = 0; r < 4; ++r) mx = fmaxf(mx, sf[u][mj][r]);
      mx = fmaxf(mx, __shfl_xor(mx, 16, 64));
      mx = fmaxf(mx, __shfl_xor(mx, 32, 64));
      need[u] = (mx > mcur[u] + 4.f);
      const float mnew = fmaxf(mcur[u], mx);
      alpha[u] = need[u] ? exp2fast(mcur[u] - mnew) : 1.f;
      const float m_use = need[u] ? mnew : mcur[u];
      float rs = 0.f;
#pragma unroll
      for (int t = 0; t < 4; ++t) {
        float e0 = exp2fast(sf[u][t][0] - m_use);
        float e1 = exp2fast(sf[u][t][1] - m_use);
        float e2 = exp2fast(sf[u][t][2] - m_use);
        float e3 = exp2fast(sf[u][t][3] - m_use);
        rs += (e0 + e1) + (e2 + e3);
        union { unsigned int w[2]; bhalf4 v; } pk;
        pk.w[0] = cvt_pk_bf16(e0, e1);
        pk.w[1] = cvt_pk_bf16(e2, e3);
        pb[u][t] = pk.v;
      }
      rs += __shfl_xor(rs, 16, 64);
      rs += __shfl_xor(rs, 32, 64);
      mcur[u] = m_use;
      lcur[u] = lcur[u] * alpha[u] + rs;
    }

    __syncthreads();           // B2: V[s] landed; all waves done QK reads
    if (!last) stageK(k0 + TK);   // K[s+1]; lands by next B1

#pragma unroll
    for (int u = 0; u < 2; ++u) {
      if (__any(need[u])) {
#pragma unroll
        for (int df = 0; df < 8; ++df)
#pragma unroll
          for (int r = 0; r < 4; ++r) o[u][df][r] *= alpha[u];
      }
    }

    // O^T += V^T * P^T; each va read feeds 2 MFMAs
    __builtin_amdgcn_s_setprio(1);
#pragma unroll
    for (int t = 0; t < 4; ++t) {
      int kc = t * 2 + (kg >> 1);
#pragma unroll
      for (int df = 0; df < 8; ++df) {
        int row = df * 16 + lm;
        bhalf4 va = *(const bhalf4*)(sVt + row * TK + (kc ^ (row & 7)) * 8 +
                                     (kg & 1) * 4);
        o[0][df] = __builtin_amdgcn_mfma_f32_16x16x16bf16_1k(va, pb[0][t], o[0][df], 0, 0, 0);
        o[1][df] = __builtin_amdgcn_mfma_f32_16x16x16bf16_1k(va, pb[1][t], o[1][df], 0, 0, 0);
      }
    }
    __builtin_amdgcn_s_setprio(0);
  }

  // epilogue per subtile: lane owns q-row, d = df*16 + kg*4 + r
#pragma unroll
  for (int u = 0; u < 2; ++u) {
    const float inv = 1.f / lcur[u];
    const size_t rowoff =
        (size_t)(b * S_ + qbase + u * 16) * QDIM_ + h * HD_ + kg * 4;
#pragma unroll
    for (int df = 0; df < 8; ++df) {
      bhalf4 w;
      w[0] = f2bf(o[u][df][0] * inv);
      w[1] = f2bf(o[u][df][1] * inv);
      w[2] = f2bf(o[u][df][2] * inv);
      w[3] = f2bf(o[u][df][3] * inv);
      *(bhalf4*)(O + rowoff + df * 16) = w;
    }
  }
}

// ---------------------------------------------------------------------------
extern "C" void kernel_launch(void* const* d_in, const int* in_sizes, int n_in,
                              void* d_out, int out_size, void* d_ws, size_t ws_size,
                              hipStream_t stream) {
  const float* x     = (const float*)d_in[0];  // [B,S,D] fp32
  const float* freqs = (const float*)d_in[1];  // [S,HD] fp32
  const float* Wqkv  = (const float*)d_in[2];  // [3072,2048] fp32
  const float* Wo    = (const float*)d_in[3];  // [2048,2048] fp32
  float* out = (float*)d_out;                  // [B,S,D] fp32

  short* ws     = (short*)d_ws;
  short* xb     = ws;                                    // 4096*2048
  short* Wob    = ws;                                    // 2048*2048 (alias xb;
                                                         //  converted after QKV GEMM)
  short* Wqkvb  = ws + (size_t)4096 * 2048;              // 3072*2048
  short* xqkv   = Wqkvb + (size_t)QKV_ * 2048;           // 4096*3072
  short* attn   = xqkv;                                  // 4096*2048 (alias)
  short* Qr     = xqkv + (size_t)4096 * QKV_;
  short* Kr     = Qr + (size_t)B_ * NH_ * S_ * HD_;
  short* Vv     = Kr + (size_t)B_ * NKV_ * S_ * HD_;
  short* Vtg    = Vv + (size_t)B_ * NKV_ * S_ * HD_;
  // total ~41.9M shorts = 83.9 MB (verified layout)

  f32_to_bf16_2<<<(4096 * 2048 / 8 + QKV_ * 2048 / 8) / 256, 256, 0, stream>>>(
      x, xb, 4096 * 2048 / 8, Wqkv, Wqkvb);
  gemm_nt_bf16<QKV_, 2048, false>
      <<<dim3(QKV_ / 128, 4096 / 128), 256, 0, stream>>>(xb, Wqkvb, xqkv);
  f32_to_bf16<<<(2048 * 2048 / 8) / 256, 256, 0, stream>>>(Wo, Wob, 2048 * 2048 / 8);
  rope_split<<<(B_ * S_ * QKV_ / 8) / 256, 256, 0, stream>>>(xqkv, freqs, Qr, Kr, Vv);
  transpose_v<<<dim3(S_ / 64, HD_ / 64, B_ * NKV_), 256, 0, stream>>>(Vv, Vtg);
  attn_causal<<<dim3(32, 16), 256, 0, stream>>>(Qr, Kr, Vtg, attn);
  gemm_nt_bf16<2048, 2048, true>
      <<<dim3(2048 / 128, 4096 / 128), 256, 0, stream>>>(attn, Wob, out);
}

// Round 11
// 315.619 us; speedup vs baseline: 1.0560x; 1.0560x over previous
//
#include <hip/hip_runtime.h>
#include <hip/hip_bf16.h>
#include <cstdint>
#include <cstddef>

#define B_ 2
#define S_ 2048
#define NH_ 16
#define NKV_ 4
#define HD_ 128
#define QDIM_ 2048
#define KVDIM_ 512
#define QKV_ 3072

typedef __attribute__((ext_vector_type(8))) short short8;
typedef __attribute__((ext_vector_type(4))) short bhalf4;   // short4 collides with HIP
typedef __attribute__((ext_vector_type(4))) float float4v;

__device__ __forceinline__ float bf2f(short u) {
  union { unsigned int i; float f; } v;
  v.i = ((unsigned int)(unsigned short)u) << 16;
  return v.f;
}
__device__ __forceinline__ short f2bf(float f) {
  union { float f; unsigned int i; } v; v.f = f;
  unsigned int x = v.i;
  x += 0x7fffu + ((x >> 16) & 1u);   // RNE
  return (short)(x >> 16);
}

#if __has_builtin(__builtin_amdgcn_exp2f)
__device__ __forceinline__ float exp2fast(float x) { return __builtin_amdgcn_exp2f(x); }
#else
__device__ __forceinline__ float exp2fast(float x) { return exp2f(x); }
#endif

// packed f32x2 -> bf16x2 (T12 recipe; no builtin on gfx950)
__device__ __forceinline__ unsigned int cvt_pk_bf16(float a, float b) {
  unsigned int r;
  asm("v_cvt_pk_bf16_f32 %0, %1, %2" : "=v"(r) : "v"(a), "v"(b));
  return r;
}

__device__ __forceinline__ void async_copy16(void* lds, const void* g) {
  __builtin_amdgcn_global_load_lds(
      (const __attribute__((address_space(1))) void*)g,
      (__attribute__((address_space(3))) void*)lds, 16, 0, 0);
}

// ---------------------------------------------------------------------------
// fp32 -> bf16 converts (HBM-bound). Range boundaries are multiples of 256
// chunks so the branches are block-uniform.
// ---------------------------------------------------------------------------
__device__ __forceinline__ void cvt8(const float* f, short* d) {
  float4v a = *(const float4v*)(f);
  float4v b = *(const float4v*)(f + 4);
  short8 r;
#pragma unroll
  for (int e = 0; e < 4; ++e) { r[e] = f2bf(a[e]); r[4 + e] = f2bf(b[e]); }
  *(short8*)d = r;
}

__global__ void f32_to_bf16(const float* __restrict__ src, short* __restrict__ dst,
                            int n8) {
  int id = blockIdx.x * 256 + threadIdx.x;
  if (id >= n8) return;
  cvt8(src + (size_t)id * 8, dst + (size_t)id * 8);
}

__global__ void f32_to_bf16_2(const float* __restrict__ s0, short* __restrict__ d0,
                              int n0_8, const float* __restrict__ s1,
                              short* __restrict__ d1) {
  int id = blockIdx.x * 256 + threadIdx.x;
  if (id < n0_8) {
    cvt8(s0 + (size_t)id * 8, d0 + (size_t)id * 8);
  } else {
    int j = id - n0_8;
    cvt8(s1 + (size_t)j * 8, d1 + (size_t)j * 8);
  }
}

__global__ void f32_to_bf16_3(const float* __restrict__ s0, short* __restrict__ d0,
                              int n0_8, const float* __restrict__ s1,
                              short* __restrict__ d1, int n1_8,
                              const float* __restrict__ s2,
                              short* __restrict__ d2) {
  int id = blockIdx.x * 256 + threadIdx.x;
  if (id < n0_8) {
    cvt8(s0 + (size_t)id * 8, d0 + (size_t)id * 8);
  } else if (id < n0_8 + n1_8) {
    int j = id - n0_8;
    cvt8(s1 + (size_t)j * 8, d1 + (size_t)j * 8);
  } else {
    int j = id - n0_8 - n1_8;
    cvt8(s2 + (size_t)j * 8, d2 + (size_t)j * 8);
  }
}

// ---------------------------------------------------------------------------
// NT GEMM, 128x128 tile (m97 structure; verified). Both GEMMs use this —
// the R8/R9 256^2 pipelined port was correct but 10 us slower (192-block
// grid = 25% idle CUs, 1 block/CU, 2-phase granularity lost the template's
// gain), so the verified kernel stays.
// ---------------------------------------------------------------------------
template <int N, int K, bool CF32>
__global__ __launch_bounds__(256)
void gemm_nt_bf16(const short* __restrict__ A, const short* __restrict__ Bm,
                  void* __restrict__ Cp) {
  __shared__ __align__(16) short sA[128 * 32];
  __shared__ __align__(16) short sB[128 * 32];
  const int tid = threadIdx.x;
  const int m0 = blockIdx.y * 128, n0 = blockIdx.x * 128;
  const int wave = tid >> 6, lane = tid & 63;
  const int wm = (wave & 1) << 6, wn = (wave >> 1) << 6;
  const int lm = lane & 15, kg = lane >> 4;

  float4v acc[4][4];
#pragma unroll
  for (int i = 0; i < 4; ++i)
#pragma unroll
    for (int j = 0; j < 4; ++j)
      acc[i][j] = (float4v){0.f, 0.f, 0.f, 0.f};

  const int r0 = tid >> 2, c0 = tid & 3;
  const short* gA0 = A + (size_t)(m0 + r0) * K + c0 * 8;
  const short* gA1 = gA0 + (size_t)64 * K;
  const short* gB0 = Bm + (size_t)(n0 + r0) * K + c0 * 8;
  const short* gB1 = gB0 + (size_t)64 * K;
  short* lA0 = sA + tid * 8;
  short* lA1 = sA + 2048 + tid * 8;
  short* lB0 = sB + tid * 8;
  short* lB1 = sB + 2048 + tid * 8;

  for (int k0 = 0; k0 < K; k0 += 32) {
    async_copy16(lA0, gA0 + k0);
    async_copy16(lA1, gA1 + k0);
    async_copy16(lB0, gB0 + k0);
    async_copy16(lB1, gB1 + k0);
    __syncthreads();

    short8 a[4], b[4];
#pragma unroll
    for (int i = 0; i < 4; ++i)
      a[i] = *(const short8*)(sA + (wm + i * 16 + lm) * 32 + kg * 8);
#pragma unroll
    for (int j = 0; j < 4; ++j)
      b[j] = *(const short8*)(sB + (wn + j * 16 + lm) * 32 + kg * 8);
#pragma unroll
    for (int i = 0; i < 4; ++i)
#pragma unroll
      for (int j = 0; j < 4; ++j)
        acc[i][j] = __builtin_amdgcn_mfma_f32_16x16x32_bf16(a[i], b[j], acc[i][j], 0, 0, 0);
    __syncthreads();
  }

#pragma unroll
  for (int i = 0; i < 4; ++i) {
    const int rb = m0 + wm + i * 16 + kg * 4;
#pragma unroll
    for (int j = 0; j < 4; ++j) {
      const int cc = n0 + wn + j * 16 + lm;
#pragma unroll
      for (int r = 0; r < 4; ++r) {
        if constexpr (CF32)
          ((float*)Cp)[(size_t)(rb + r) * N + cc] = acc[i][j][r];
        else
          ((short*)Cp)[(size_t)(rb + r) * N + cc] = f2bf(acc[i][j][r]);
      }
    }
  }
}

// ---------------------------------------------------------------------------
// RoPE + split/layout; Q pre-scaled by (1/sqrt(HD)) * log2(e).
// ---------------------------------------------------------------------------
__global__ void rope_split(const short* __restrict__ xqkv, const float* __restrict__ freqs,
                           short* __restrict__ Qr, short* __restrict__ Kr,
                           short* __restrict__ Vv) {
  const int id = blockIdx.x * 256 + threadIdx.x;
  const int i = id / (QKV_ / 8);   // token 0..4095
  const int c8 = id % (QKV_ / 8);
  const int col = c8 * 8;
  const int b = i >> 11, s = i & (S_ - 1);
  short8 xv = *(const short8*)(xqkv + (size_t)i * QKV_ + col);
  if (col < QDIM_ + KVDIM_) {
    int d;
    short* dst;
    float sc;
    if (col < QDIM_) {
      int hh = col >> 7; d = col & 127;
      dst = Qr + ((size_t)(b * NH_ + hh) * S_ + s) * HD_ + d;
      sc = 0.12751744543795287f;   // (1/sqrt(128)) * log2(e)
    } else {
      int cc = col - QDIM_;
      int hh = cc >> 7; d = cc & 127;
      dst = Kr + ((size_t)(b * NKV_ + hh) * S_ + s) * HD_ + d;
      sc = 1.0f;
    }
    const float* fp = freqs + (size_t)s * HD_ + d;
    float4v fa = *(const float4v*)(fp);
    float4v fb = *(const float4v*)(fp + 4);
    float ff[8] = {fa[0], fa[1], fa[2], fa[3], fb[0], fb[1], fb[2], fb[3]};
    short8 ov;
#pragma unroll
    for (int pp = 0; pp < 4; ++pp) {
      float t0 = bf2f(xv[2 * pp]), t1 = bf2f(xv[2 * pp + 1]);
      float f0 = ff[2 * pp], f1 = ff[2 * pp + 1];
      ov[2 * pp]     = f2bf((t0 * f1 - t1 * f0) * sc);
      ov[2 * pp + 1] = f2bf((t0 * f0 + t1 * f1) * sc);
    }
    *(short8*)dst = ov;
  } else {
    int cc = col - QDIM_ - KVDIM_;
    int hh = cc >> 7, d = cc & 127;
    *(short8*)(Vv + ((size_t)(b * NKV_ + hh) * S_ + s) * HD_ + d) = xv;
  }
}

// ---------------------------------------------------------------------------
// V transpose: Vv [b][kvh][s][d] -> Vt [b][kvh][d][s]. LDS-tiled 64x64.
// ---------------------------------------------------------------------------
__global__ void transpose_v(const short* __restrict__ Vv, short* __restrict__ Vt) {
  __shared__ short t[64][72];
  const int s0 = blockIdx.x * 64, d0 = blockIdx.y * 64;
  const short* src = Vv + (size_t)blockIdx.z * S_ * HD_;
  short* dst = Vt + (size_t)blockIdx.z * S_ * HD_;
  const int tid = threadIdx.x;
#pragma unroll
  for (int c = 0; c < 2; ++c) {
    int ch = tid + 256 * c;
    int row = ch >> 3, kc = ch & 7;
    *(short8*)(&t[row][kc * 8]) =
        *(const short8*)(src + (size_t)(s0 + row) * HD_ + d0 + kc * 8);
  }
  __syncthreads();
#pragma unroll
  for (int c = 0; c < 2; ++c) {
    int ch = tid + 256 * c;
    int drow = ch >> 3, sc = ch & 7;
    short8 w;
#pragma unroll
    for (int j = 0; j < 8; ++j) w[j] = t[sc * 8 + j][drow];
    *(short8*)(dst + (size_t)(d0 + drow) * S_ + s0 + sc * 8) = w;
  }
}

// ---------------------------------------------------------------------------
// Flash attention v10 (per-dispatch best, 87.5 us stable across 6 runs):
// 2 q-subtiles/wave, QBLK=128, TK=64. Each LDS K/V fragment read feeds 2
// MFMAs (conflicts halved vs v8, no spill at VGPR 104). exp2-domain
// softmax, defer-max THR=4, cvt_pk P->bf16.
// ---------------------------------------------------------------------------
#define TK 64

__global__ __launch_bounds__(256, 2)
void attn_causal(const short* __restrict__ Q, const short* __restrict__ K,
                 const short* __restrict__ Vt, short* __restrict__ O) {
  const int bh = blockIdx.x;                 // 0..31
  const int by = blockIdx.y;                 // 0..15
  const int qt = (by < 8) ? (15 - by) : (by - 8);   // LPT pairing
  const int b = bh >> 4, h = bh & 15;
  const int kvh = h >> 2;
  const int tid = threadIdx.x, wave = tid >> 6, lane = tid & 63;
  const int lm = lane & 15, kg = lane >> 4;

  __shared__ __align__(16) short sK[TK * HD_];    // 16 KB, swizzled
  __shared__ __align__(16) short sVt[HD_ * TK];   // 16 KB, swizzled

  const short* Qb = Q + (size_t)(b * NH_ + h) * S_ * HD_;
  const short* Kb = K + (size_t)(b * NKV_ + kvh) * S_ * HD_;
  const short* Vtb = Vt + (size_t)(b * NKV_ + kvh) * S_ * HD_;

  auto stageK = [&](int k0) {
#pragma unroll
    for (int c = 0; c < 4; ++c) {
      int ch = tid + 256 * c;
      int row = ch >> 4, kc = ch & 15;
      async_copy16(sK + ch * 8,
                   Kb + (size_t)(k0 + row) * HD_ + (kc ^ (row & 7)) * 8);
    }
  };
  auto stageV = [&](int k0) {
#pragma unroll
    for (int c = 0; c < 4; ++c) {
      int ch = tid + 256 * c;
      int row = ch >> 3, kc = ch & 7;
      async_copy16(sVt + ch * 8,
                   Vtb + (size_t)row * S_ + k0 + (kc ^ (row & 7)) * 8);
    }
  };

  // wave owns 32 contiguous q rows: rows qbase + u*16, u = 0,1
  const int qbase = qt * 128 + wave * 32 + lm;
  short8 qf[2][4];
#pragma unroll
  for (int u = 0; u < 2; ++u)
#pragma unroll
    for (int kk = 0; kk < 4; ++kk)
      qf[u][kk] = *(const short8*)(Qb + (size_t)(qbase + u * 16) * HD_ +
                                   kk * 32 + kg * 8);

  float mcur[2] = {-1e9f, -1e9f}, lcur[2] = {0.f, 0.f};
  float4v o[2][8];
#pragma unroll
  for (int u = 0; u < 2; ++u)
#pragma unroll
    for (int df = 0; df < 8; ++df) o[u][df] = (float4v){0.f, 0.f, 0.f, 0.f};

  stageK(0);
  const int nst = 2 * qt + 2;
  for (int s = 0; s < nst; ++s) {
    const int k0 = s * TK;
    const bool last = (s == nst - 1);
    const bool maskstep = (s >= nst - 2);   // 128-row tile spans 2 diag tiles

    __syncthreads();           // B1: K[s] landed; all waves done PV[s-1]
    stageV(k0);                // V[s]; lands by B2

    // S^T = K * Q^T for both q-subtiles; each af read feeds 2 MFMAs
    float4v sf[2][4];
#pragma unroll
    for (int u = 0; u < 2; ++u)
#pragma unroll
      for (int mj = 0; mj < 4; ++mj) sf[u][mj] = (float4v){0.f, 0.f, 0.f, 0.f};
    __builtin_amdgcn_s_setprio(1);
#pragma unroll
    for (int kk = 0; kk < 4; ++kk) {
      int kd = kk * 4 + kg;
#pragma unroll
      for (int mj = 0; mj < 4; ++mj) {
        int row = mj * 16 + lm;
        short8 af = *(const short8*)(sK + row * HD_ + (kd ^ (row & 7)) * 8);
        sf[0][mj] = __builtin_amdgcn_mfma_f32_16x16x32_bf16(af, qf[0][kk], sf[0][mj], 0, 0, 0);
        sf[1][mj] = __builtin_amdgcn_mfma_f32_16x16x32_bf16(af, qf[1][kk], sf[1][mj], 0, 0, 0);
      }
    }
    __builtin_amdgcn_s_setprio(0);

    if (maskstep) {   // causal mask, per subtile (harmless where all pass)
#pragma unroll
      for (int u = 0; u < 2; ++u) {
        const int qg = qbase + u * 16;
#pragma unroll
        for (int mj = 0; mj < 4; ++mj)
#pragma unroll
          for (int r = 0; r < 4; ++r) {
            int kcol = k0 + mj * 16 + kg * 4 + r;
            sf[u][mj][r] = (kcol <= qg) ? sf[u][mj][r] : -3e38f;
          }
      }
    }

    // online softmax (exp2 domain), defer-max THR=4, per subtile
    bhalf4 pb[2][4];
    bool need[2];
    float alpha[2];
#pragma unroll
    for (int u = 0; u < 2; ++u) {
      float mx = -3e38f;
#pragma unroll
      for (int mj = 0; mj < 4; ++mj)
#pragma unroll
        for (int r = 0; r < 4; ++r) mx = fmaxf(mx, sf[u][mj][r]);
      mx = fmaxf(mx, __shfl_xor(mx, 16, 64));
      mx = fmaxf(mx, __shfl_xor(mx, 32, 64));
      need[u] = (mx > mcur[u] + 4.f);
      const float mnew = fmaxf(mcur[u], mx);
      alpha[u] = need[u] ? exp2fast(mcur[u] - mnew) : 1.f;
      const float m_use = need[u] ? mnew : mcur[u];
      float rs = 0.f;
#pragma unroll
      for (int t = 0; t < 4; ++t) {
        float e0 = exp2fast(sf[u][t][0] - m_use);
        float e1 = exp2fast(sf[u][t][1] - m_use);
        float e2 = exp2fast(sf[u][t][2] - m_use);
        float e3 = exp2fast(sf[u][t][3] - m_use);
        rs += (e0 + e1) + (e2 + e3);
        union { unsigned int w[2]; bhalf4 v; } pk;
        pk.w[0] = cvt_pk_bf16(e0, e1);
        pk.w[1] = cvt_pk_bf16(e2, e3);
        pb[u][t] = pk.v;
      }
      rs += __shfl_xor(rs, 16, 64);
      rs += __shfl_xor(rs, 32, 64);
      mcur[u] = m_use;
      lcur[u] = lcur[u] * alpha[u] + rs;
    }

    __syncthreads();           // B2: V[s] landed; all waves done QK reads
    if (!last) stageK(k0 + TK);   // K[s+1]; lands by next B1

#pragma unroll
    for (int u = 0; u < 2; ++u) {
      if (__any(need[u])) {
#pragma unroll
        for (int df = 0; df < 8; ++df)
#pragma unroll
          for (int r = 0; r < 4; ++r) o[u][df][r] *= alpha[u];
      }
    }

    // O^T += V^T * P^T; each va read feeds 2 MFMAs
    __builtin_amdgcn_s_setprio(1);
#pragma unroll
    for (int t = 0; t < 4; ++t) {
      int kc = t * 2 + (kg >> 1);
#pragma unroll
      for (int df = 0; df < 8; ++df) {
        int row = df * 16 + lm;
        bhalf4 va = *(const bhalf4*)(sVt + row * TK + (kc ^ (row & 7)) * 8 +
                                     (kg & 1) * 4);
        o[0][df] = __builtin_amdgcn_mfma_f32_16x16x16bf16_1k(va, pb[0][t], o[0][df], 0, 0, 0);
        o[1][df] = __builtin_amdgcn_mfma_f32_16x16x16bf16_1k(va, pb[1][t], o[1][df], 0, 0, 0);
      }
    }
    __builtin_amdgcn_s_setprio(0);
  }

  // epilogue per subtile: lane owns q-row, d = df*16 + kg*4 + r
#pragma unroll
  for (int u = 0; u < 2; ++u) {
    const float inv = 1.f / lcur[u];
    const size_t rowoff =
        (size_t)(b * S_ + qbase + u * 16) * QDIM_ + h * HD_ + kg * 4;
#pragma unroll
    for (int df = 0; df < 8; ++df) {
      bhalf4 w;
      w[0] = f2bf(o[u][df][0] * inv);
      w[1] = f2bf(o[u][df][1] * inv);
      w[2] = f2bf(o[u][df][2] * inv);
      w[3] = f2bf(o[u][df][3] * inv);
      *(bhalf4*)(O + rowoff + df * 16) = w;
    }
  }
}

// ---------------------------------------------------------------------------
extern "C" void kernel_launch(void* const* d_in, const int* in_sizes, int n_in,
                              void* d_out, int out_size, void* d_ws, size_t ws_size,
                              hipStream_t stream) {
  const float* x     = (const float*)d_in[0];  // [B,S,D] fp32
  const float* freqs = (const float*)d_in[1];  // [S,HD] fp32
  const float* Wqkv  = (const float*)d_in[2];  // [3072,2048] fp32
  const float* Wo    = (const float*)d_in[3];  // [2048,2048] fp32
  float* out = (float*)d_out;                  // [B,S,D] fp32

  short* ws     = (short*)d_ws;
  short* xb     = ws;                                    // 4096*2048
  short* Wqkvb  = ws + (size_t)4096 * 2048;              // 3072*2048
  short* xqkv   = Wqkvb + (size_t)QKV_ * 2048;           // 4096*3072
  short* attn   = xqkv;                                  // 4096*2048 (alias)
  short* Qr     = xqkv + (size_t)4096 * QKV_;
  short* Kr     = Qr + (size_t)B_ * NH_ * S_ * HD_;
  short* Vv     = Kr + (size_t)B_ * NKV_ * S_ * HD_;
  short* Vtg    = Vv + (size_t)B_ * NKV_ * S_ * HD_;
  short* wsEnd  = Vtg + (size_t)B_ * NKV_ * S_ * HD_;    // 41,943,040 shorts

  constexpr int NX8 = 4096 * 2048 / 8;    // 1,048,576 chunks (x)
  constexpr int NW8 = QKV_ * 2048 / 8;    //   786,432 chunks (Wqkv)
  constexpr int NO8 = 2048 * 2048 / 8;    //   524,288 chunks (Wo)

  // If the workspace fits a non-aliased Wob (92.3 MB), convert all three
  // tensors in ONE launch up front and drop the mid-pipeline Wo convert
  // (it otherwise serializes between the QKV GEMM and rope_split because
  // Wob aliases xb). Fallback = exact R10 pipeline.
  const bool bigWs =
      ws_size >= (size_t)(41943040 + 2048 * 2048) * sizeof(short);
  short* Wob = bigWs ? wsEnd : xb;   // alias xb only in the fallback

  if (bigWs) {
    f32_to_bf16_3<<<(NX8 + NW8 + NO8) / 256, 256, 0, stream>>>(
        x, xb, NX8, Wqkv, Wqkvb, NW8, Wo, Wob);
    gemm_nt_bf16<QKV_, 2048, false>
        <<<dim3(QKV_ / 128, 4096 / 128), 256, 0, stream>>>(xb, Wqkvb, xqkv);
  } else {
    f32_to_bf16_2<<<(NX8 + NW8) / 256, 256, 0, stream>>>(x, xb, NX8, Wqkv, Wqkvb);
    gemm_nt_bf16<QKV_, 2048, false>
        <<<dim3(QKV_ / 128, 4096 / 128), 256, 0, stream>>>(xb, Wqkvb, xqkv);
    f32_to_bf16<<<NO8 / 256, 256, 0, stream>>>(Wo, Wob, NO8);
  }
  rope_split<<<(B_ * S_ * QKV_ / 8) / 256, 256, 0, stream>>>(xqkv, freqs, Qr, Kr, Vv);
  transpose_v<<<dim3(S_ / 64, HD_ / 64, B_ * NKV_), 256, 0, stream>>>(Vv, Vtg);
  attn_causal<<<dim3(32, 16), 256, 0, stream>>>(Qr, Kr, Vtg, attn);
  gemm_nt_bf16<2048, 2048, true>
      <<<dim3(2048 / 128, 4096 / 128), 256, 0, stream>>>(attn, Wob, out);
}